// Round 1
// 205.428 us; speedup vs baseline: 1.0409x; 1.0409x over previous
//
#include <hip/hip_runtime.h>
#include <math.h>

#define T_SEQ 2048
#define D_MODEL 2048
#define HEAD_DIM 64
#define N_HEADS 32
#define N_KV 8

using short8 = __attribute__((ext_vector_type(8))) short;
using f32x4  = __attribute__((ext_vector_type(4))) float;
using f32x16 = __attribute__((ext_vector_type(16))) float;
using u32x4  = __attribute__((ext_vector_type(4))) unsigned int;

#define MFMA16(a, b, c) __builtin_amdgcn_mfma_f32_16x16x32_bf16(a, b, c, 0, 0, 0)
#define MFMA32(a, b, c) __builtin_amdgcn_mfma_f32_32x32x16_bf16(a, b, c, 0, 0, 0)

__device__ __forceinline__ unsigned short f2bf(float f) {
    unsigned int u = __builtin_bit_cast(unsigned int, f);
    u += 0x7fff + ((u >> 16) & 1);
    return (unsigned short)(u >> 16);
}
__device__ __forceinline__ void gld_lds16(const ushort* g, ushort* l) {
    __builtin_amdgcn_global_load_lds((const __attribute__((address_space(1))) void*)g,
                                     (__attribute__((address_space(3))) void*)l, 16, 0, 0);
}
// pack two f32 -> one u32 of 2 bf16 (RTNE), single instruction
__device__ __forceinline__ unsigned int cvtpk(float lo, float hi) {
    unsigned int r;
    asm("v_cvt_pk_bf16_f32 %0, %1, %2" : "=v"(r) : "v"(lo), "v"(hi));
    return r;
}
// exchange: a' = {a.lo32, b.lo32 from lane-32}; b' = {a.hi32 from lane+32, b.hi32}
__device__ __forceinline__ void plswap(unsigned int& a, unsigned int& b) {
    auto r = __builtin_amdgcn_permlane32_swap(a, b, false, false);
    a = r[0];
    b = r[1];
}

// ---------------------------------------------------------------------------
// RoPE tables (llama3 scaling), fp32, transposed [i][T]. 256-thread blocks.
// ---------------------------------------------------------------------------
__global__ __launch_bounds__(256) void rope_tables_kernel(float* __restrict__ cosT, float* __restrict__ sinT,
                                                          const int* __restrict__ start_pos, int T) {
    int idx = blockIdx.x * 256 + threadIdx.x;
    int t = idx >> 5;
    int i = idx & 31;
    float pos = (float)(start_pos[0] + t);
    float expo = (float)i / 32.0f;
    float inv_freq = 1.0f / powf(500000.0f, expo);
    const float two_pi = 6.283185307179586f;
    float wavelen = two_pi / inv_freq;
    const float low_wl = 8192.0f;
    const float high_wl = 2048.0f;
    float inv;
    if (wavelen > low_wl) {
        inv = inv_freq / 32.0f;
    } else if (wavelen < high_wl) {
        inv = inv_freq;
    } else {
        float smooth = (8192.0f / wavelen - 1.0f) / 3.0f;
        inv = (1.0f - smooth) * (inv_freq / 32.0f) + smooth * inv_freq;
    }
    float ang = pos * inv;
    cosT[i * T + t] = cosf(ang);
    sinT[i * T + t] = sinf(ang);
}

// ---------------------------------------------------------------------------
// One cast kernel for all five fp32->bf16 conversions (float4 granules)
// ---------------------------------------------------------------------------
__global__ __launch_bounds__(256) void cast_all_kernel(
    const float* __restrict__ x, const float* __restrict__ wq,
    const float* __restrict__ wk, const float* __restrict__ wv,
    const float* __restrict__ wo,
    ushort* __restrict__ xb, ushort* __restrict__ wqb,
    ushort* __restrict__ wkb, ushort* __restrict__ wvb, ushort* __restrict__ wob) {
    int i = blockIdx.x * 256 + threadIdx.x;
    const float* src; ushort* dst; int off;
    if (i < 1048576)      { src = x;  dst = xb;  off = i; }
    else if (i < 2097152) { src = wq; dst = wqb; off = i - 1048576; }
    else if (i < 2359296) { src = wk; dst = wkb; off = i - 2097152; }
    else if (i < 2621440) { src = wv; dst = wvb; off = i - 2359296; }
    else                  { src = wo; dst = wob; off = i - 2621440; }
    float4 v = ((const float4*)src)[off];
    ushort4 o;
    o.x = f2bf(v.x); o.y = f2bf(v.y); o.z = f2bf(v.z); o.w = f2bf(v.w);
    ((ushort4*)dst)[off] = o;
}

// ---------------------------------------------------------------------------
// Fused QKV GEMM + RoPE epilogue. 64x128 tile, BK=64 as 2x BK=32 sub-tiles
// per barrier, dbuf, XOR-swizzled. Grid 32 x 24 = 768 blocks (3/CU).
// grid.y: 0..15 Q, 16..19 K, 20..23 V(transposed)
// Q outputs are pre-scaled by log2(e)/8 so attention uses a bare exp2.
// ---------------------------------------------------------------------------
__global__ __launch_bounds__(256) void gemm_qkv(
    const ushort* __restrict__ X, const ushort* __restrict__ Wqb,
    const ushort* __restrict__ Wkb, const ushort* __restrict__ Wvb,
    ushort* __restrict__ Qo, ushort* __restrict__ Ko, ushort* __restrict__ Vto,
    const float* __restrict__ cosT, const float* __restrict__ sinT,
    int T, int D) {
    __shared__ __align__(16) ushort As[2][2][2048];   // [buf][sub][64x32]
    __shared__ __align__(16) ushort Bs[2][2][4096];   // [buf][sub][128x32]
    const int tid = threadIdx.x;
    const int w = tid >> 6, l = tid & 63;
    const int m0 = blockIdx.x * 64;
    const int n0g = blockIdx.y * 128;

    const ushort* B;
    ushort* Cout;
    int n0, doRope;
    if (n0g < 2048)      { B = Wqb + (size_t)n0g * D;          Cout = Qo;  n0 = n0g;        doRope = 1; }
    else if (n0g < 2560) { B = Wkb + (size_t)(n0g - 2048) * D; Cout = Ko;  n0 = n0g - 2048; doRope = 1; }
    else                 { B = Wvb + (size_t)(n0g - 2560) * D; Cout = Vto; n0 = n0g - 2560; doRope = 0; }

    const int wm = (w >> 1) * 32, wn = (w & 1) * 64;
    const int lr = l & 15;
    const int quad = l >> 4;

    f32x4 zero = {0.f, 0.f, 0.f, 0.f};
    f32x4 acc[2][4];
#pragma unroll
    for (int i = 0; i < 2; ++i)
#pragma unroll
        for (int j = 0; j < 4; ++j) acc[i][j] = zero;

    const int srow = l >> 2;                       // 0..15
    const int scg  = ((l & 3) ^ (srow & 3)) * 8;   // swizzled global chunk
    const ushort* Ag  = X + (size_t)(m0 + 16 * w + srow) * D + scg;
    const ushort* Bg0 = B + (size_t)(16 * (2 * w) + srow) * D + scg;
    const ushort* Bg1 = B + (size_t)(16 * (2 * w + 1) + srow) * D + scg;

#define GSTAGE(k0v, nb) { \
    gld_lds16(Ag  + (k0v),      &As[nb][0][w * 512]); \
    gld_lds16(Ag  + (k0v) + 32, &As[nb][1][w * 512]); \
    gld_lds16(Bg0 + (k0v),      &Bs[nb][0][(2 * w) * 512]); \
    gld_lds16(Bg0 + (k0v) + 32, &Bs[nb][1][(2 * w) * 512]); \
    gld_lds16(Bg1 + (k0v),      &Bs[nb][0][(2 * w + 1) * 512]); \
    gld_lds16(Bg1 + (k0v) + 32, &Bs[nb][1][(2 * w + 1) * 512]); }

    GSTAGE(0, 0);

    const int rsw = (quad ^ (lr & 3)) * 8;
    for (int k0 = 0; k0 < D; k0 += 64) {
        const int b = (k0 >> 6) & 1;
        __syncthreads();
        if (k0 + 64 < D) GSTAGE(k0 + 64, b ^ 1);
#pragma unroll
        for (int sub = 0; sub < 2; ++sub) {
            short8 af[2], bf[4];
#pragma unroll
            for (int i = 0; i < 2; ++i) af[i] = *(const short8*)&As[b][sub][(wm + i * 16 + lr) * 32 + rsw];
#pragma unroll
            for (int j = 0; j < 4; ++j) bf[j] = *(const short8*)&Bs[b][sub][(wn + j * 16 + lr) * 32 + rsw];
#pragma unroll
            for (int i = 0; i < 2; ++i)
#pragma unroll
                for (int j = 0; j < 4; ++j)
                    acc[i][j] = MFMA16(af[i], bf[j], acc[i][j]);
        }
    }
#undef GSTAGE

    const int mbase = m0 + wm + quad * 4;
    if (doRope) {
        // fold softmax scale (1/8) and log2(e) into Q only
        const float qsc = (n0g < 2048) ? 0.18033688011112042f : 1.0f;
#pragma unroll
        for (int i = 0; i < 2; ++i) {
            int trow = mbase + i * 16;
#pragma unroll
            for (int j = 0; j < 2; ++j) {
                int i1 = lr + j * 16;
                float4 c4 = *(const float4*)&cosT[(size_t)i1 * T + trow];
                float4 s4 = *(const float4*)&sinT[(size_t)i1 * T + trow];
                int n1 = n0 + wn + lr + j * 16;
                int n2 = n1 + 32;
                size_t b1 = (size_t)(n1 >> 6) * ((size_t)T * 64) + (size_t)(n1 & 63);
                size_t b2 = (size_t)(n2 >> 6) * ((size_t)T * 64) + (size_t)(n2 & 63);
                float cs[4] = {c4.x, c4.y, c4.z, c4.w};
                float sn[4] = {s4.x, s4.y, s4.z, s4.w};
#pragma unroll
                for (int r = 0; r < 4; ++r) {
                    float x1 = acc[i][j][r], x2 = acc[i][j + 2][r];
                    Cout[b1 + (size_t)(trow + r) * 64] = f2bf((x1 * cs[r] - x2 * sn[r]) * qsc);
                    Cout[b2 + (size_t)(trow + r) * 64] = f2bf((x2 * cs[r] + x1 * sn[r]) * qsc);
                }
            }
        }
    } else {
#pragma unroll
        for (int i = 0; i < 2; ++i)
#pragma unroll
            for (int j = 0; j < 4; ++j) {
                int n = n0 + wn + lr + j * 16;
                int m = mbase + i * 16;
                ushort4 o;
                o.x = f2bf(acc[i][j][0]); o.y = f2bf(acc[i][j][1]);
                o.z = f2bf(acc[i][j][2]); o.w = f2bf(acc[i][j][3]);
                *(ushort4*)&Vto[(size_t)n * T + m] = o;
            }
    }
}

// ---------------------------------------------------------------------------
// Output projection GEMM (C fp32), same BK=64 dual-sub-tile core
// ---------------------------------------------------------------------------
__global__ __launch_bounds__(256) void gemm_bt_f32(const ushort* __restrict__ A,
                                                   const ushort* __restrict__ B,
                                                   float* __restrict__ C,
                                                   int M, int N, int K) {
    __shared__ __align__(16) ushort As[2][2][2048];
    __shared__ __align__(16) ushort Bs[2][2][4096];
    const int tid = threadIdx.x;
    const int w = tid >> 6, l = tid & 63;
    const int m0 = blockIdx.x * 64, n0 = blockIdx.y * 128;
    const int wm = (w >> 1) * 32, wn = (w & 1) * 64;
    const int lr = l & 15;
    const int quad = l >> 4;

    f32x4 zero = {0.f, 0.f, 0.f, 0.f};
    f32x4 acc[2][4];
#pragma unroll
    for (int i = 0; i < 2; ++i)
#pragma unroll
        for (int j = 0; j < 4; ++j) acc[i][j] = zero;

    const int srow = l >> 2;
    const int scg  = ((l & 3) ^ (srow & 3)) * 8;
    const ushort* Ag  = A + (size_t)(m0 + 16 * w + srow) * K + scg;
    const ushort* Bg0 = B + (size_t)(n0 + 16 * (2 * w) + srow) * K + scg;
    const ushort* Bg1 = B + (size_t)(n0 + 16 * (2 * w + 1) + srow) * K + scg;

#define GSTAGE(k0v, nb) { \
    gld_lds16(Ag  + (k0v),      &As[nb][0][w * 512]); \
    gld_lds16(Ag  + (k0v) + 32, &As[nb][1][w * 512]); \
    gld_lds16(Bg0 + (k0v),      &Bs[nb][0][(2 * w) * 512]); \
    gld_lds16(Bg0 + (k0v) + 32, &Bs[nb][1][(2 * w) * 512]); \
    gld_lds16(Bg1 + (k0v),      &Bs[nb][0][(2 * w + 1) * 512]); \
    gld_lds16(Bg1 + (k0v) + 32, &Bs[nb][1][(2 * w + 1) * 512]); }

    GSTAGE(0, 0);

    const int rsw = (quad ^ (lr & 3)) * 8;
    for (int k0 = 0; k0 < K; k0 += 64) {
        const int b = (k0 >> 6) & 1;
        __syncthreads();
        if (k0 + 64 < K) GSTAGE(k0 + 64, b ^ 1);
#pragma unroll
        for (int sub = 0; sub < 2; ++sub) {
            short8 af[2], bf[4];
#pragma unroll
            for (int i = 0; i < 2; ++i) af[i] = *(const short8*)&As[b][sub][(wm + i * 16 + lr) * 32 + rsw];
#pragma unroll
            for (int j = 0; j < 4; ++j) bf[j] = *(const short8*)&Bs[b][sub][(wn + j * 16 + lr) * 32 + rsw];
#pragma unroll
            for (int i = 0; i < 2; ++i)
#pragma unroll
                for (int j = 0; j < 4; ++j)
                    acc[i][j] = MFMA16(af[i], bf[j], acc[i][j]);
        }
    }
#undef GSTAGE

    const int mbase = m0 + wm + quad * 4;
    const int nbase = n0 + wn + lr;
#pragma unroll
    for (int i = 0; i < 2; ++i)
#pragma unroll
        for (int j = 0; j < 4; ++j)
#pragma unroll
            for (int r = 0; r < 4; ++r)
                C[(size_t)(mbase + i * 16 + r) * N + (nbase + j * 16)] = acc[i][j][r];
}

// ---------------------------------------------------------------------------
// Flash attention, 32x32x16 MFMA rewrite.
//   Block = 128 threads (2 waves), each wave owns 32 q-rows; QBLK = 64.
//   Grid (32, 32) = 1024 blocks -> 4/CU all-resident; causal balance via
//   h-parity qb remap (CU's 4 blocks pair qb with 31-qb).
//   S^T = K @ Q^T (swapped): lane owns P[key block][q = lane&31] in regs.
//   P -> PV B-operand redistribution fully in-register (T12):
//   v_cvt_pk_bf16_f32 pairs + v_permlane32_swap_b32 (no Ps LDS at all).
//   O^T = V^T @ P^T: lane's D column = its own q-row -> lane-local 1/sum.
//   K/V double-buffered in LDS (32 KB), chunk-XOR-swizzled (T2), staged via
//   global_load_lds with pre-swizzled global source.
//   Q pre-scaled by log2(e)/8 in gemm_qkv -> softmax exp = single v_exp_f32.
// ---------------------------------------------------------------------------
__global__ __launch_bounds__(128, 2) void attn_mfma(const ushort* __restrict__ Q,
                                                    const ushort* __restrict__ K,
                                                    const ushort* __restrict__ Vt,
                                                    ushort* __restrict__ ctx, int T) {
    __shared__ __align__(16) ushort Ks[2][4096];   // [key64][dim64], chunk-swizzled
    __shared__ __align__(16) ushort Vs[2][4096];   // [dim64][key64], chunk-swizzled
    const int tid = threadIdx.x, w = tid >> 6, l = tid & 63;
    const int lq = l & 31, hi = l >> 5;
    const int h = blockIdx.y, hk = h >> 2;
    const int qb = ((h >> 3) & 1) ? (31 - (int)blockIdx.x) : (int)blockIdx.x;
    const int ntiles = qb + 1;
    const ushort* Kb = K + (size_t)hk * T * 64;
    const ushort* Vb = Vt + (size_t)hk * 64 * T;

    const int srow = l >> 3;                 // 0..7
    const int sc   = ((l & 7) ^ srow) * 8;   // pre-swizzled global chunk offset

    // Q fragments (B operand): q-row = qb*64 + w*32 + lq; dims ks*16 + hi*8 + j
    const ushort* Qrow = Q + ((size_t)h * T + qb * 64 + w * 32 + lq) * 64;
    short8 qf[4];
#pragma unroll
    for (int ks = 0; ks < 4; ++ks)
        qf[ks] = *(const short8*)(Qrow + ks * 16 + hi * 8);

    f32x16 oacc0, oacc1;
#pragma unroll
    for (int r = 0; r < 16; ++r) { oacc0[r] = 0.f; oacc1[r] = 0.f; }
    float ls[4] = {0.f, 0.f, 0.f, 0.f};
    const int limit = w * 32 + lq;           // local q-row within the 64-row q-tile

#define ASTAGE(kt, buf) do { \
    size_t _k0 = (size_t)(kt) * 64; \
    const int _s0 = w * 4; \
    gld_lds16(Kb + (_k0 + _s0 * 8      + srow) * 64 + sc, &Ks[buf][(_s0    ) * 512]); \
    gld_lds16(Kb + (_k0 + _s0 * 8 + 8  + srow) * 64 + sc, &Ks[buf][(_s0 + 1) * 512]); \
    gld_lds16(Kb + (_k0 + _s0 * 8 + 16 + srow) * 64 + sc, &Ks[buf][(_s0 + 2) * 512]); \
    gld_lds16(Kb + (_k0 + _s0 * 8 + 24 + srow) * 64 + sc, &Ks[buf][(_s0 + 3) * 512]); \
    gld_lds16(Vb + (size_t)(_s0 * 8      + srow) * T + _k0 + sc, &Vs[buf][(_s0    ) * 512]); \
    gld_lds16(Vb + (size_t)(_s0 * 8 + 8  + srow) * T + _k0 + sc, &Vs[buf][(_s0 + 1) * 512]); \
    gld_lds16(Vb + (size_t)(_s0 * 8 + 16 + srow) * T + _k0 + sc, &Vs[buf][(_s0 + 2) * 512]); \
    gld_lds16(Vb + (size_t)(_s0 * 8 + 24 + srow) * T + _k0 + sc, &Vs[buf][(_s0 + 3) * 512]); \
} while (0)

    ASTAGE(0, 0);

    for (int kt = 0; kt < ntiles; ++kt) {
        const int b = kt & 1;
        __syncthreads();
        if (kt + 1 < ntiles) ASTAGE(kt + 1, b ^ 1);

        // S^T = K @ Q^T -> D[key][q]; lane: col q = lq, rows crow(r,hi)+32*mb
        f32x16 s0, s1;
#pragma unroll
        for (int r = 0; r < 16; ++r) { s0[r] = 0.f; s1[r] = 0.f; }
#pragma unroll
        for (int ks = 0; ks < 4; ++ks) {
            const int c = ((ks * 2 + hi) ^ (lq & 7)) * 8;
            short8 kf0 = *(const short8*)&Ks[b][lq * 64 + c];
            short8 kf1 = *(const short8*)&Ks[b][(lq + 32) * 64 + c];
            s0 = MFMA32(kf0, qf[ks], s0);
            s1 = MFMA32(kf1, qf[ks], s1);
        }

        // p = exp2(s) (Q pre-scaled by log2e/8); diag tile masks key > q
        f32x16 p0, p1;
        if (kt == ntiles - 1) {
#pragma unroll
            for (int r = 0; r < 16; ++r) {
                const int kk = (r & 3) + 8 * (r >> 2) + 4 * hi;
                p0[r] = (kk <= limit)      ? __builtin_amdgcn_exp2f(s0[r]) : 0.f;
                p1[r] = (kk + 32 <= limit) ? __builtin_amdgcn_exp2f(s1[r]) : 0.f;
            }
        } else {
#pragma unroll
            for (int r = 0; r < 16; ++r) {
                p0[r] = __builtin_amdgcn_exp2f(s0[r]);
                p1[r] = __builtin_amdgcn_exp2f(s1[r]);
            }
        }
#pragma unroll
        for (int r = 0; r < 16; ++r) ls[r & 3] += p0[r] + p1[r];

        // O^T += V^T @ P^T. B-frag for step ks2 needs keys 16*ks2+8*hi+j of
        // own q-row; built in-register: cvt_pk pairs + permlane32_swap.
#pragma unroll
        for (int ks2 = 0; ks2 < 4; ++ks2) {
            const f32x16& pp = (ks2 < 2) ? p0 : p1;
            const int bse = (ks2 & 1) * 8;
            unsigned int a0 = cvtpk(pp[bse + 0], pp[bse + 1]);
            unsigned int a1 = cvtpk(pp[bse + 2], pp[bse + 3]);
            unsigned int b0 = cvtpk(pp[bse + 4], pp[bse + 5]);
            unsigned int b1 = cvtpk(pp[bse + 6], pp[bse + 7]);
            plswap(a0, b0);
            plswap(a1, b1);
            u32x4 tw = {a0, a1, b0, b1};
            short8 pf = __builtin_bit_cast(short8, tw);
            const int c = ((ks2 * 2 + hi) ^ (lq & 7)) * 8;
            short8 vf0 = *(const short8*)&Vs[b][lq * 64 + c];
            short8 vf1 = *(const short8*)&Vs[b][(lq + 32) * 64 + c];
            oacc0 = MFMA32(vf0, pf, oacc0);
            oacc1 = MFMA32(vf1, pf, oacc1);
        }
    }
#undef ASTAGE

    // denominator: lane + its hi-partner hold the full row sum for q = lq
    float vsum = (ls[0] + ls[1]) + (ls[2] + ls[3]);
    vsum += __shfl_xor(vsum, 32, 64);
    const float inv = 1.f / vsum;

    // O^T lane layout: col = own q-row; rows d = (r&3)+8*(r>>2)+4*hi (+32)
    ushort* cp = ctx + (size_t)(qb * 64 + w * 32 + lq) * 2048 + h * 64;
#pragma unroll
    for (int g = 0; g < 4; ++g) {
        ushort4 o0, o1;
        o0.x = f2bf(oacc0[4 * g + 0] * inv); o0.y = f2bf(oacc0[4 * g + 1] * inv);
        o0.z = f2bf(oacc0[4 * g + 2] * inv); o0.w = f2bf(oacc0[4 * g + 3] * inv);
        *(ushort4*)&cp[g * 8 + hi * 4] = o0;
        o1.x = f2bf(oacc1[4 * g + 0] * inv); o1.y = f2bf(oacc1[4 * g + 1] * inv);
        o1.z = f2bf(oacc1[4 * g + 2] * inv); o1.w = f2bf(oacc1[4 * g + 3] * inv);
        *(ushort4*)&cp[32 + g * 8 + hi * 4] = o1;
    }
}

// ---------------------------------------------------------------------------
extern "C" void kernel_launch(void* const* d_in, const int* in_sizes, int n_in,
                              void* d_out, int out_size, void* d_ws, size_t ws_size,
                              hipStream_t stream) {
    const float* x  = (const float*)d_in[0];
    const float* Wq = (const float*)d_in[1];
    const float* Wk = (const float*)d_in[2];
    const float* Wv = (const float*)d_in[3];
    const float* Wo = (const float*)d_in[4];
    const int* start_pos = (const int*)d_in[5];
    float* out = (float*)d_out;

    const int T = T_SEQ, D = D_MODEL;
    const int KV = N_KV * HEAD_DIM;  // 512

    char* w = (char*)d_ws;
    float* cosT = (float*)w;            w += (size_t)32 * T * 4;
    float* sinT = (float*)w;            w += (size_t)32 * T * 4;
    ushort* xbf  = (ushort*)w;          w += (size_t)T * D * 2;     // aliased: ctx
    ushort* wqbf = (ushort*)w;          w += (size_t)D * D * 2;
    ushort* wkbf = (ushort*)w;          w += (size_t)KV * D * 2;
    ushort* wvbf = (ushort*)w;          w += (size_t)KV * D * 2;
    ushort* wobf = (ushort*)w;          w += (size_t)D * D * 2;
    ushort* qbf  = (ushort*)w;          w += (size_t)N_HEADS * T * 64 * 2;
    ushort* kbf  = (ushort*)w;          w += (size_t)N_KV * T * 64 * 2;
    ushort* vtbf = (ushort*)w;          w += (size_t)N_KV * 64 * T * 2;
    ushort* ctxbf = xbf;  // x fully consumed by gemm_qkv before attn writes ctx

    rope_tables_kernel<<<dim3((T * 32) / 256), dim3(256), 0, stream>>>(cosT, sinT, start_pos, T);

    cast_all_kernel<<<dim3(14336), dim3(256), 0, stream>>>(x, Wq, Wk, Wv, Wo,
                                                           xbf, wqbf, wkbf, wvbf, wobf);

    gemm_qkv<<<dim3(T / 64, (D + 2 * KV) / 128), dim3(256), 0, stream>>>(
        xbf, wqbf, wkbf, wvbf, qbf, kbf, vtbf, cosT, sinT, T, D);

    attn_mfma<<<dim3(32, N_HEADS), dim3(128), 0, stream>>>(qbf, kbf, vtbf, ctxbf, T);

    gemm_bt_f32<<<dim3(T / 64, D / 128), dim3(256), 0, stream>>>(ctxbf, wobf, out, T, D, D);
}